// Round 1
// baseline (352.151 us; speedup 1.0000x reference)
//
#include <hip/hip_runtime.h>
#include <math.h>

#define H 768
#define L 256
#define NB 4
#define NL 13

// ---------------- Stage 1: fp32 tiled GEMM -----------------------------------
// P = X(1024x768) @ [W1a | W1b](768x1536).
// n<768  -> xs' = X@W1[:H] + b1, stored row-major [m][k]   (m = b*L+s)
// n>=768 -> xe  = X@W1[H:],      stored transposed [b][k][j=s] for stage-2 coalescing
#define BM 64
#define BN 64
#define BK 16

__global__ __launch_bounds__(256) void gemm1_kernel(
    const float* __restrict__ X, const float* __restrict__ W1,
    const float* __restrict__ b1, float* __restrict__ Pxs, float* __restrict__ PxeT)
{
    __shared__ float As[BK][BM + 4];   // +4 pad: <=2-way bank aliasing (free), keeps 16B align
    __shared__ float Bs[BK][BN + 4];
    const int tid = threadIdx.x;
    const int m0 = blockIdx.x * BM;
    const int n0 = blockIdx.y * BN;
    const bool isE = (n0 >= H);
    const float* Wb = W1 + (isE ? (size_t)H * H : 0);
    const int nc0 = isE ? (n0 - H) : n0;
    const int ty = tid >> 4;   // 0..15, owns rows ty*4..ty*4+3
    const int tx = tid & 15;   // 0..15, owns cols tx*4..tx*4+3

    float acc[4][4] = {};
    for (int k0 = 0; k0 < H; k0 += BK) {
        #pragma unroll
        for (int r = 0; r < 4; ++r) {
            int m = (tid >> 4) + 16 * r;
            int k = tid & 15;
            As[k][m] = X[(size_t)(m0 + m) * H + k0 + k];
        }
        #pragma unroll
        for (int r = 0; r < 4; ++r) {
            int k = (tid >> 6) + 4 * r;
            int n = tid & 63;
            Bs[k][n] = Wb[(size_t)(k0 + k) * H + nc0 + n];
        }
        __syncthreads();
        #pragma unroll
        for (int kk = 0; kk < BK; ++kk) {
            const float4 a4 = *(const float4*)&As[kk][ty * 4];
            const float4 b4 = *(const float4*)&Bs[kk][tx * 4];
            const float av[4] = {a4.x, a4.y, a4.z, a4.w};
            const float bv[4] = {b4.x, b4.y, b4.z, b4.w};
            #pragma unroll
            for (int r = 0; r < 4; ++r)
                #pragma unroll
                for (int c = 0; c < 4; ++c)
                    acc[r][c] = fmaf(av[r], bv[c], acc[r][c]);
        }
        __syncthreads();
    }

    if (!isE) {
        #pragma unroll
        for (int r = 0; r < 4; ++r) {
            int m = m0 + ty * 4 + r;
            int n = n0 + tx * 4;
            float4 v = { acc[r][0] + b1[n + 0], acc[r][1] + b1[n + 1],
                         acc[r][2] + b1[n + 2], acc[r][3] + b1[n + 3] };
            *(float4*)&Pxs[(size_t)m * H + n] = v;
        }
    } else {
        #pragma unroll
        for (int r = 0; r < 4; ++r) {
            int m = m0 + ty * 4 + r;
            int bb = m >> 8, s = m & 255;
            #pragma unroll
            for (int c = 0; c < 4; ++c) {
                int k = nc0 + tx * 4 + c;
                PxeT[((size_t)bb * H + k) * L + s] = acc[r][c];
            }
        }
    }
}

// ---------------- Stage 2: fused broadcast-add + exact GELU + W2 matvec ------
// block = (b,i); thread = j. logits[b,i,j,n] = sum_k gelu(xs'[i,k]+xe[j,k]) * W2[k,n] + b2[n]
__global__ __launch_bounds__(256) void span_kernel(
    const float* __restrict__ Pxs, const float* __restrict__ PxeT,
    const float* __restrict__ W2, const float* __restrict__ b2,
    float* __restrict__ out)
{
    __shared__ float xs[H];
    const int bi = blockIdx.x;          // b*L + i
    const int b = bi >> 8;
    const int j = threadIdx.x;

    for (int t = threadIdx.x; t < H; t += 256) xs[t] = Pxs[(size_t)bi * H + t];
    __syncthreads();

    const float* xe = PxeT + (size_t)b * H * L + j;
    float acc[NL];
    #pragma unroll
    for (int n = 0; n < NL; ++n) acc[n] = 0.f;

    for (int k = 0; k < H; k += 4) {
        float e[4];
        #pragma unroll
        for (int u = 0; u < 4; ++u) e[u] = xe[(size_t)(k + u) * L];
        #pragma unroll
        for (int u = 0; u < 4; ++u) {
            float h = xs[k + u] + e[u];
            float g = 0.5f * h * (1.0f + erff(h * 0.70710678118654752f));
            #pragma unroll
            for (int n = 0; n < NL; ++n)
                acc[n] = fmaf(g, W2[(size_t)(k + u) * NL + n], acc[n]);
        }
    }

    float* o = out + ((size_t)bi * L + j) * NL;
    #pragma unroll
    for (int n = 0; n < NL; ++n) o[n] = acc[n] + b2[n];
}

// ---------------- Launch ------------------------------------------------------
extern "C" void kernel_launch(void* const* d_in, const int* in_sizes, int n_in,
                              void* d_out, int out_size, void* d_ws, size_t ws_size,
                              hipStream_t stream)
{
    (void)in_sizes; (void)n_in; (void)out_size; (void)ws_size;
    const float* X  = (const float*)d_in[0];
    const float* W1 = (const float*)d_in[1];
    const float* b1 = (const float*)d_in[2];
    const float* W2 = (const float*)d_in[3];
    const float* b2 = (const float*)d_in[4];
    float* out = (float*)d_out;

    float* Pxs  = (float*)d_ws;                       // 1024*768 fp32 = 3 MB
    float* PxeT = Pxs + (size_t)NB * L * H;           // 4*768*256 fp32 = 3 MB

    dim3 g1((NB * L) / BM, (2 * H) / BN);             // 16 x 24
    gemm1_kernel<<<g1, 256, 0, stream>>>(X, W1, b1, Pxs, PxeT);
    span_kernel<<<NB * L, 256, 0, stream>>>(Pxs, PxeT, W2, b2, out);
}

// Round 2
// 211.801 us; speedup vs baseline: 1.6626x; 1.6626x over previous
//
#include <hip/hip_runtime.h>
#include <math.h>

#define H 768
#define L 256
#define NB 4
#define NL 13

typedef short bf16x8 __attribute__((ext_vector_type(8)));
typedef float f32x4 __attribute__((ext_vector_type(4)));

// RNE float -> bf16 (bits)
__device__ inline unsigned int f2bf_bits(float f) {
    unsigned int u = __builtin_bit_cast(unsigned int, f);
    u += 0x7fffu + ((u >> 16) & 1u);
    return u >> 16;
}
__device__ inline float bfbits2f(unsigned int hi) {
    return __builtin_bit_cast(float, hi << 16);
}

// tanh-form GELU: 0.5x(1+tanh(0.79788456(x+0.044715x^3))), tanh via exp2
__device__ inline float gelu_f(float x) {
    float x2 = x * x;
    float z  = x * fmaf(x2, 0.1029435f, 2.3022087f);  // 2*0.79788456*log2(e)*(1+0.044715x^2)
    z = fminf(fmaxf(z, -60.f), 60.f);
    float t  = __builtin_amdgcn_exp2f(z);             // e^{2*arg}
    float r  = __builtin_amdgcn_rcpf(t + 1.f);
    float th = (t - 1.f) * r;                          // tanh
    float hx = 0.5f * x;
    return fmaf(hx, th, hx);
}

// ---------------- Stage 1: fp32 tiled GEMM -----------------------------------
// n<768  -> Pxs = X@W1[:H] + b1, fp32 row-major [b*L+i][k]
// n>=768 -> Pxe = X@W1[H:],      bf16 row-major [b*L+j][k]
#define BM 64
#define BN 64
#define BK 16

__global__ __launch_bounds__(256) void gemm1_kernel(
    const float* __restrict__ X, const float* __restrict__ W1,
    const float* __restrict__ b1, float* __restrict__ Pxs,
    unsigned short* __restrict__ Pxe)
{
    __shared__ float As[BK][BM + 4];
    __shared__ float Bs[BK][BN + 4];
    const int tid = threadIdx.x;
    const int m0 = blockIdx.x * BM;
    const int n0 = blockIdx.y * BN;
    const bool isE = (n0 >= H);
    const float* Wb = W1 + (isE ? (size_t)H * H : 0);
    const int nc0 = isE ? (n0 - H) : n0;
    const int ty = tid >> 4;
    const int tx = tid & 15;

    float acc[4][4] = {};
    for (int k0 = 0; k0 < H; k0 += BK) {
        #pragma unroll
        for (int r = 0; r < 4; ++r) {
            int m = (tid >> 4) + 16 * r;
            int k = tid & 15;
            As[k][m] = X[(size_t)(m0 + m) * H + k0 + k];
        }
        #pragma unroll
        for (int r = 0; r < 4; ++r) {
            int k = (tid >> 6) + 4 * r;
            int n = tid & 63;
            Bs[k][n] = Wb[(size_t)(k0 + k) * H + nc0 + n];
        }
        __syncthreads();
        #pragma unroll
        for (int kk = 0; kk < BK; ++kk) {
            const float4 a4 = *(const float4*)&As[kk][ty * 4];
            const float4 b4 = *(const float4*)&Bs[kk][tx * 4];
            const float av[4] = {a4.x, a4.y, a4.z, a4.w};
            const float bv[4] = {b4.x, b4.y, b4.z, b4.w};
            #pragma unroll
            for (int r = 0; r < 4; ++r)
                #pragma unroll
                for (int c = 0; c < 4; ++c)
                    acc[r][c] = fmaf(av[r], bv[c], acc[r][c]);
        }
        __syncthreads();
    }

    if (!isE) {
        #pragma unroll
        for (int r = 0; r < 4; ++r) {
            int m = m0 + ty * 4 + r;
            int n = n0 + tx * 4;
            float4 v = { acc[r][0] + b1[n + 0], acc[r][1] + b1[n + 1],
                         acc[r][2] + b1[n + 2], acc[r][3] + b1[n + 3] };
            *(float4*)&Pxs[(size_t)m * H + n] = v;
        }
    } else {
        #pragma unroll
        for (int r = 0; r < 4; ++r) {
            int m = m0 + ty * 4 + r;        // m = b*L + j
            int k = nc0 + tx * 4;
            unsigned int p0 = (f2bf_bits(acc[r][1]) << 16) | f2bf_bits(acc[r][0]);
            unsigned int p1 = (f2bf_bits(acc[r][3]) << 16) | f2bf_bits(acc[r][2]);
            uint2 v = {p0, p1};
            *(uint2*)&Pxe[(size_t)m * H + k] = v;   // 8B store, bf16 x4
        }
    }
}

// ---------------- W2 fragment prep -------------------------------------------
// Bfrag[kb][lane][u] = bf16(W2[kb*32 + (lane>>4)*8 + u][lane&15]), n>=13 -> 0
__global__ __launch_bounds__(256) void prep_w2_kernel(
    const float* __restrict__ W2, unsigned short* __restrict__ Bfrag)
{
    int idx = blockIdx.x * 256 + threadIdx.x;       // 0 .. 24*64*8-1
    if (idx >= (H / 32) * 64 * 8) return;
    int u = idx & 7;
    int lane = (idx >> 3) & 63;
    int kb = idx >> 9;
    int k = kb * 32 + ((lane >> 4) << 3) + u;
    int n = lane & 15;
    float v = (n < NL) ? W2[(size_t)k * NL + n] : 0.f;
    Bfrag[idx] = (unsigned short)f2bf_bits(v);
}

// ---------------- Stage 2: fused gelu + MFMA W2 reduction --------------------
// block = (b,i): M=256 (j), N=16 (13 labels padded), K=768.
// wave w handles j in [64w, 64w+64): 4 m-tiles of 16.
__global__ __launch_bounds__(256) void span_mfma_kernel(
    const float* __restrict__ Pxs, const unsigned short* __restrict__ Pxe,
    const unsigned short* __restrict__ Bfrag, const float* __restrict__ b2,
    float* __restrict__ out)
{
    __shared__ float xs[H];
    const int bi = blockIdx.x;          // b*L + i
    const int b = bi >> 8;
    const int tid = threadIdx.x;
    for (int t = tid; t < H; t += 256) xs[t] = Pxs[(size_t)bi * H + t];  // b1 already folded in

    const int wave = tid >> 6;
    const int lane = tid & 63;
    const int n = lane & 15;
    const int quad = lane >> 4;

    const unsigned short* xerow[4];
    #pragma unroll
    for (int t = 0; t < 4; ++t) {
        int j = wave * 64 + t * 16 + n;             // A-frag row m = lane&15
        xerow[t] = Pxe + (size_t)(b * L + j) * H;
    }

    f32x4 acc[4] = {};
    __syncthreads();

    for (int kb = 0; kb < H / 32; ++kb) {
        const int k8 = kb * 32 + quad * 8;          // this lane's 8 consecutive k
        bf16x8 bfrag = *(const bf16x8*)(Bfrag + ((size_t)kb * 64 + lane) * 8);
        float4 xsa = *(const float4*)&xs[k8];
        float4 xsb = *(const float4*)&xs[k8 + 4];
        const float xsv[8] = {xsa.x, xsa.y, xsa.z, xsa.w, xsb.x, xsb.y, xsb.z, xsb.w};

        #pragma unroll
        for (int t = 0; t < 4; ++t) {
            uint4 xev = *(const uint4*)(xerow[t] + k8);     // 8 bf16 = 16B
            const unsigned int xw[4] = {xev.x, xev.y, xev.z, xev.w};
            float g[8];
            #pragma unroll
            for (int p = 0; p < 4; ++p) {
                float e0 = bfbits2f(xw[p] & 0xffffu);
                float e1 = bfbits2f(xw[p] >> 16);
                g[2 * p + 0] = gelu_f(xsv[2 * p + 0] + e0);
                g[2 * p + 1] = gelu_f(xsv[2 * p + 1] + e1);
            }
            unsigned int pk[4];
            #pragma unroll
            for (int p = 0; p < 4; ++p)
                pk[p] = (f2bf_bits(g[2 * p + 1]) << 16) | f2bf_bits(g[2 * p]);
            uint4 pk4 = {pk[0], pk[1], pk[2], pk[3]};
            bf16x8 afrag = __builtin_bit_cast(bf16x8, pk4);
            acc[t] = __builtin_amdgcn_mfma_f32_16x16x32_bf16(afrag, bfrag, acc[t], 0, 0, 0);
        }
    }

    // Epilogue: C/D layout col = lane&15 (= label n), row = quad*4 + reg
    if (n < NL) {
        float b2v = b2[n];
        #pragma unroll
        for (int t = 0; t < 4; ++t) {
            #pragma unroll
            for (int r = 0; r < 4; ++r) {
                int j = wave * 64 + t * 16 + quad * 4 + r;
                out[((size_t)bi * L + j) * NL + n] = acc[t][r] + b2v;
            }
        }
    }
}

// ---------------- Launch ------------------------------------------------------
extern "C" void kernel_launch(void* const* d_in, const int* in_sizes, int n_in,
                              void* d_out, int out_size, void* d_ws, size_t ws_size,
                              hipStream_t stream)
{
    (void)in_sizes; (void)n_in; (void)out_size; (void)ws_size;
    const float* X  = (const float*)d_in[0];
    const float* W1 = (const float*)d_in[1];
    const float* b1 = (const float*)d_in[2];
    const float* W2 = (const float*)d_in[3];
    const float* b2 = (const float*)d_in[4];
    float* out = (float*)d_out;

    char* ws = (char*)d_ws;
    float* Pxs = (float*)ws;                                   // 1024*768*4 = 3 MB
    unsigned short* Pxe = (unsigned short*)(ws + (size_t)NB * L * H * 4);   // 1.5 MB
    unsigned short* Bfrag = Pxe + (size_t)NB * L * H;          // 24 KB

    prep_w2_kernel<<<48, 256, 0, stream>>>(W2, Bfrag);
    dim3 g1((NB * L) / BM, (2 * H) / BN);
    gemm1_kernel<<<g1, 256, 0, stream>>>(X, W1, b1, Pxs, Pxe);
    span_mfma_kernel<<<NB * L, 256, 0, stream>>>(Pxs, Pxe, Bfrag, b2, out);
}

// Round 3
// 174.751 us; speedup vs baseline: 2.0152x; 1.2120x over previous
//
#include <hip/hip_runtime.h>
#include <math.h>

#define H 768
#define L 256
#define NB 4
#define NL 13

typedef short bf16x8 __attribute__((ext_vector_type(8)));
typedef float f32x4 __attribute__((ext_vector_type(4)));

// RNE float -> bf16 (bits) — used in prep/epilogue only (not hot)
__device__ inline unsigned int f2bf_bits(float f) {
    unsigned int u = __builtin_bit_cast(unsigned int, f);
    u += 0x7fffu + ((u >> 16) & 1u);
    return u >> 16;
}
__device__ inline float bfbits2f(unsigned int hi) {
    return __builtin_bit_cast(float, hi << 16);
}

// tanh-form GELU, exp2-based. No negative clamp needed: exp2(-inf)=0 -> th=-1.
__device__ inline float gelu_f(float x) {
    float x2 = x * x;
    float z  = x * fmaf(x2, 0.1029435f, 2.3022087f);   // 2*log2(e)*0.79788456*(1+0.044715x^2)
    z = fminf(z, 120.f);                                // only +inf overflow is dangerous
    float t  = __builtin_amdgcn_exp2f(z);
    float r  = __builtin_amdgcn_rcpf(t + 1.f);
    float th = fmaf(t, r, -r);                          // (t-1)/(t+1)
    float hx = 0.5f * x;
    return fmaf(hx, th, hx);
}

// pack two f32 -> bf16x2 dword with +0x8000 (round-half-up) via v_perm
__device__ inline unsigned int pack_bf2(float g0, float g1) {
    unsigned int u0 = __builtin_bit_cast(unsigned int, g0) + 0x8000u;
    unsigned int u1 = __builtin_bit_cast(unsigned int, g1) + 0x8000u;
    return __builtin_amdgcn_perm(u1, u0, 0x07060302u);  // {u1.hi16, u0.hi16}
}

// ---------------- Prep: W1 transpose->bf16, X->bf16, W2 frags ----------------
// Combined W1 view: Ball[h][n'] (n' in [0,1536)) = W1[h + 768*(n'>=768)][n'%768]
// W1T[n'][h] bf16.  Xbf[m][k] bf16.  Bfrag as in R2.
#define TP_NT (1536 / 32)
#define TP_NH (768 / 32)
#define TP_NBLK (TP_NT * TP_NH)          // 1152
#define XC_NBLK 768                       // 1024*768 / (256*4)
#define W2_NBLK 48

__global__ __launch_bounds__(256) void prep_kernel(
    const float* __restrict__ W1, const float* __restrict__ X,
    const float* __restrict__ W2,
    unsigned short* __restrict__ W1T, unsigned short* __restrict__ Xbf,
    unsigned short* __restrict__ Bfrag)
{
    const int blk = blockIdx.x;
    const int tid = threadIdx.x;

    if (blk < TP_NBLK) {
        // --- 32x32 transpose tile ---
        __shared__ unsigned short tile[32][33];
        int tn = blk / TP_NH, th = blk % TP_NH;
        int np0 = tn * 32, h0 = th * 32;
        int off = (np0 >= H) ? H : 0;
        int c0 = np0 - ((np0 >= H) ? H : 0);
        // load: rows = h (W1 row h+off), cols = n (W1 col c0+lc)
        int lr = tid >> 3, lc = (tid & 7) * 4;
        float4 v = *(const float4*)&W1[(size_t)(off + h0 + lr) * H + c0 + lc];
        tile[lr][lc + 0] = (unsigned short)f2bf_bits(v.x);
        tile[lr][lc + 1] = (unsigned short)f2bf_bits(v.y);
        tile[lr][lc + 2] = (unsigned short)f2bf_bits(v.z);
        tile[lr][lc + 3] = (unsigned short)f2bf_bits(v.w);
        __syncthreads();
        // write: W1T[np0+wr][h0+wc..+4]
        int wr = tid >> 3, wc = (tid & 7) * 4;
        ushort4 o;
        o.x = tile[wc + 0][wr];
        o.y = tile[wc + 1][wr];
        o.z = tile[wc + 2][wr];
        o.w = tile[wc + 3][wr];
        *(ushort4*)&W1T[(size_t)(np0 + wr) * H + h0 + wc] = o;
    } else if (blk < TP_NBLK + XC_NBLK) {
        // --- X fp32 -> bf16, 4 elems/thread ---
        int idx = ((blk - TP_NBLK) * 256 + tid) * 4;
        float4 v = *(const float4*)&X[idx];
        ushort4 o;
        o.x = (unsigned short)f2bf_bits(v.x);
        o.y = (unsigned short)f2bf_bits(v.y);
        o.z = (unsigned short)f2bf_bits(v.z);
        o.w = (unsigned short)f2bf_bits(v.w);
        *(ushort4*)&Xbf[idx] = o;
    } else {
        // --- W2 B-fragments: Bfrag[kb][lane][u] ---
        int idx = (blk - TP_NBLK - XC_NBLK) * 256 + tid;   // < 24*64*8
        int u = idx & 7;
        int lane = (idx >> 3) & 63;
        int kb = idx >> 9;
        int k = kb * 32 + ((lane >> 4) << 3) + u;
        int n = lane & 15;
        float v = (n < NL) ? W2[(size_t)k * NL + n] : 0.f;
        Bfrag[idx] = (unsigned short)f2bf_bits(v);
    }
}

// ---------------- Stage 1: MFMA GEMM, no LDS ---------------------------------
// C[m][n'] = sum_k Xbf[m][k] * W1T[n'][k];  n'<768 -> Pxs (fp32, +b1), else Pxe (bf16)
__global__ __launch_bounds__(256) void gemm1_mfma(
    const unsigned short* __restrict__ Xbf, const unsigned short* __restrict__ W1T,
    const float* __restrict__ b1, float* __restrict__ Pxs,
    unsigned short* __restrict__ Pxe)
{
    const int tid = threadIdx.x;
    const int wave = tid >> 6, lane = tid & 63;
    const int ln = lane & 15, quad = lane >> 4;
    const int m0 = blockIdx.x * 64 + (wave & 1) * 32;
    const int n0 = blockIdx.y * 64 + (wave >> 1) * 32;   // n' in [0,1536)

    const unsigned short* pa0 = Xbf + (size_t)(m0 + ln) * H + quad * 8;
    const unsigned short* pa1 = pa0 + (size_t)16 * H;
    const unsigned short* pb0 = W1T + (size_t)(n0 + ln) * H + quad * 8;
    const unsigned short* pb1 = pb0 + (size_t)16 * H;

    f32x4 acc[2][2] = {};
    #pragma unroll 4
    for (int kb = 0; kb < H / 32; ++kb) {
        const int ko = kb * 32;
        bf16x8 a0 = *(const bf16x8*)(pa0 + ko);
        bf16x8 a1 = *(const bf16x8*)(pa1 + ko);
        bf16x8 b0 = *(const bf16x8*)(pb0 + ko);
        bf16x8 b1v = *(const bf16x8*)(pb1 + ko);
        acc[0][0] = __builtin_amdgcn_mfma_f32_16x16x32_bf16(a0, b0, acc[0][0], 0, 0, 0);
        acc[0][1] = __builtin_amdgcn_mfma_f32_16x16x32_bf16(a0, b1v, acc[0][1], 0, 0, 0);
        acc[1][0] = __builtin_amdgcn_mfma_f32_16x16x32_bf16(a1, b0, acc[1][0], 0, 0, 0);
        acc[1][1] = __builtin_amdgcn_mfma_f32_16x16x32_bf16(a1, b1v, acc[1][1], 0, 0, 0);
    }

    // C/D: col = lane&15 (n-offset), row = quad*4 + r (m-offset)
    if (blockIdx.y < 12) {
        float bv[2] = { b1[n0 + ln], b1[n0 + 16 + ln] };
        #pragma unroll
        for (int mt = 0; mt < 2; ++mt)
            #pragma unroll
            for (int nt = 0; nt < 2; ++nt) {
                int n = n0 + nt * 16 + ln;
                #pragma unroll
                for (int r = 0; r < 4; ++r) {
                    int m = m0 + mt * 16 + quad * 4 + r;
                    Pxs[(size_t)m * H + n] = acc[mt][nt][r] + bv[nt];
                }
            }
    } else {
        #pragma unroll
        for (int mt = 0; mt < 2; ++mt)
            #pragma unroll
            for (int nt = 0; nt < 2; ++nt) {
                int n = n0 - H + nt * 16 + ln;
                #pragma unroll
                for (int r = 0; r < 4; ++r) {
                    int m = m0 + mt * 16 + quad * 4 + r;
                    Pxe[(size_t)m * H + n] = (unsigned short)f2bf_bits(acc[mt][nt][r]);
                }
            }
    }
}

// ---------------- Stage 2: fused gelu + MFMA W2 reduction --------------------
// grid 2048: block = (b,i,jhalf). 4 waves x 2 m-tiles = 128 j per block.
__global__ __launch_bounds__(256, 6) void span_mfma_kernel(
    const float* __restrict__ Pxs, const unsigned short* __restrict__ Pxe,
    const unsigned short* __restrict__ Bfrag, const float* __restrict__ b2,
    float* __restrict__ out)
{
    __shared__ float xs[H];
    const int bi = blockIdx.x >> 1;          // b*L + i
    const int jh = blockIdx.x & 1;
    const int b = bi >> 8;
    const int tid = threadIdx.x;
    for (int t = tid; t < H; t += 256) xs[t] = Pxs[(size_t)bi * H + t];

    const int wave = tid >> 6;
    const int lane = tid & 63;
    const int n = lane & 15;
    const int quad = lane >> 4;
    const int j_base = jh * 128 + wave * 32;

    const unsigned short* xerow[2];
    #pragma unroll
    for (int t = 0; t < 2; ++t)
        xerow[t] = Pxe + (size_t)(b * L + j_base + t * 16 + n) * H;

    f32x4 acc[2] = {};
    __syncthreads();

    for (int kb = 0; kb < H / 32; ++kb) {
        const int k8 = kb * 32 + quad * 8;
        bf16x8 bfrag = *(const bf16x8*)(Bfrag + ((size_t)kb * 64 + lane) * 8);
        float4 xsa = *(const float4*)&xs[k8];
        float4 xsb = *(const float4*)&xs[k8 + 4];
        const float xsv[8] = {xsa.x, xsa.y, xsa.z, xsa.w, xsb.x, xsb.y, xsb.z, xsb.w};

        #pragma unroll
        for (int t = 0; t < 2; ++t) {
            uint4 xev = *(const uint4*)(xerow[t] + k8);
            const unsigned int xw[4] = {xev.x, xev.y, xev.z, xev.w};
            unsigned int pk[4];
            #pragma unroll
            for (int p = 0; p < 4; ++p) {
                float e0 = __builtin_bit_cast(float, xw[p] << 16);
                float e1 = __builtin_bit_cast(float, xw[p] & 0xffff0000u);
                float g0 = gelu_f(xsv[2 * p + 0] + e0);
                float g1 = gelu_f(xsv[2 * p + 1] + e1);
                pk[p] = pack_bf2(g0, g1);
            }
            uint4 pk4 = {pk[0], pk[1], pk[2], pk[3]};
            bf16x8 afrag = __builtin_bit_cast(bf16x8, pk4);
            acc[t] = __builtin_amdgcn_mfma_f32_16x16x32_bf16(afrag, bfrag, acc[t], 0, 0, 0);
        }
    }

    if (n < NL) {
        float b2v = b2[n];
        #pragma unroll
        for (int t = 0; t < 2; ++t)
            #pragma unroll
            for (int r = 0; r < 4; ++r) {
                int j = j_base + t * 16 + quad * 4 + r;
                out[((size_t)bi * L + j) * NL + n] = acc[t][r] + b2v;
            }
    }
}

// ---------------- Launch ------------------------------------------------------
extern "C" void kernel_launch(void* const* d_in, const int* in_sizes, int n_in,
                              void* d_out, int out_size, void* d_ws, size_t ws_size,
                              hipStream_t stream)
{
    (void)in_sizes; (void)n_in; (void)out_size; (void)ws_size;
    const float* X  = (const float*)d_in[0];
    const float* W1 = (const float*)d_in[1];
    const float* b1 = (const float*)d_in[2];
    const float* W2 = (const float*)d_in[3];
    const float* b2 = (const float*)d_in[4];
    float* out = (float*)d_out;

    char* ws = (char*)d_ws;
    float* Pxs = (float*)ws;                                            // 3 MB
    unsigned short* Pxe  = (unsigned short*)(ws + (size_t)NB * L * H * 4);      // 1.5 MB
    unsigned short* Xbf  = Pxe + (size_t)NB * L * H;                    // 1.5 MB
    unsigned short* W1T  = Xbf + (size_t)NB * L * H;                    // 2.25 MB
    unsigned short* Bfrag = W1T + (size_t)2 * H * H;                    // 24 KB

    prep_kernel<<<TP_NBLK + XC_NBLK + W2_NBLK, 256, 0, stream>>>(W1, X, W2, W1T, Xbf, Bfrag);
    gemm1_mfma<<<dim3(16, 24), 256, 0, stream>>>(Xbf, W1T, b1, Pxs, Pxe);
    span_mfma_kernel<<<NB * L * 2, 256, 0, stream>>>(Pxs, Pxe, Bfrag, b2, out);
}

// Round 4
// 155.462 us; speedup vs baseline: 2.2652x; 1.1241x over previous
//
#include <hip/hip_runtime.h>
#include <math.h>

#define H 768
#define L 256
#define NB 4
#define NL 13

typedef short bf16x8 __attribute__((ext_vector_type(8)));
typedef float f32x4 __attribute__((ext_vector_type(4)));

// RNE float -> bf16 (bits)
__device__ inline unsigned int f2bf_bits(float f) {
    unsigned int u = __builtin_bit_cast(unsigned int, f);
    u += 0x7fffu + ((u >> 16) & 1u);
    return u >> 16;
}

// pack two f32 -> bf16x2 dword with +0x8000 (round-half-up) via v_perm
__device__ inline unsigned int pack_bf2(float g0, float g1) {
    unsigned int u0 = __builtin_bit_cast(unsigned int, g0) + 0x8000u;
    unsigned int u1 = __builtin_bit_cast(unsigned int, g1) + 0x8000u;
    return __builtin_amdgcn_perm(u1, u0, 0x07060302u);  // {u1.hi16, u0.hi16}
}

// Polynomial GELU: erf(x/sqrt2) ~= xc*P(xc^2), xc = clamp(x,+-3.75).
// Degree-4 in u (Chebyshev-node interp on u in [0,14.06]); |err(gelu)| <= ~6e-3.
// gelu = 0.5x + 0.5x*t,  t = xc*P(u).  9 full-rate VALU ops, no transcendentals.
__device__ inline float gelu_poly(float x) {
    float xc = fminf(3.75f, fmaxf(-3.75f, x));   // v_med3
    float u  = xc * xc;
    float p  = fmaf(u, fmaf(u, fmaf(u, fmaf(u, 2.0333e-5f, -0.00084672f),
                                    0.0140002f), -0.1234557f), 0.7946463f);
    float t  = xc * p;
    float hx = 0.5f * x;
    return fmaf(hx, t, hx);
}

// ---------------- Kernel 1: fused prep + MFMA GEMM ---------------------------
// grid (16, 25).  by<24: C[m][n'] = sum_k X[m][k]*W1view[k][n'] over k=768,
//   n'<768 -> Pxs fp32 (+b1), n'>=768 -> Pxe bf16 row-major [m][n].
//   A-frags read fp32 X directly (bf16 pack in-register); B staged via LDS
//   transpose tile (fp32 coalesced-ish load -> bf16 LDS [n][k], pitch 40).
// by==24: 16 blocks build W2 B-fragments (Bfrag[kb][lane][u]).
__global__ __launch_bounds__(256) void gemm_fused(
    const float* __restrict__ X, const float* __restrict__ W1,
    const float* __restrict__ b1, const float* __restrict__ W2,
    float* __restrict__ Pxs, unsigned short* __restrict__ Pxe,
    unsigned short* __restrict__ Bfrag)
{
    const int tid = threadIdx.x;

    if (blockIdx.y == 24) {
        int base = blockIdx.x * 768 + tid;
        #pragma unroll
        for (int r = 0; r < 3; ++r) {
            int idx = base + r * 256;            // < 12288
            int u = idx & 7;
            int lane = (idx >> 3) & 63;
            int kb = idx >> 9;
            int k = kb * 32 + ((lane >> 4) << 3) + u;
            int n = lane & 15;
            float v = (n < NL) ? W2[(size_t)k * NL + n] : 0.f;
            Bfrag[idx] = (unsigned short)f2bf_bits(v);
        }
        return;
    }

    __shared__ unsigned short Bs[64][40];        // [n][k], pitch 80B (16B-aligned rows)
    const int w = tid >> 6, lane = tid & 63;
    const int ln = lane & 15, quad = lane >> 4;
    const int m0 = blockIdx.x * 64 + (w & 1) * 32;
    const int n0g = blockIdx.y * 64;             // n' in [0,1536)
    const bool isE = n0g >= H;
    const float* Wb = W1 + (isE ? (size_t)H * H : 0);
    const int nc0 = isE ? (n0g - H) : n0g;
    const int nw = (w >> 1) * 32;

    // B-stage indexing: quarter-wave shares column group, lanes span k-rows
    const int sr = tid & 15;                     // k-row within 16
    const int scq = tid >> 4;                    // 0..15 -> n-group of 4

    f32x4 acc[2][2] = {};
    for (int kb = 0; kb < H / 32; ++kb) {
        const int k0 = kb * 32;
        // ---- stage B tile: W1[k0..k0+32][nc0..nc0+64] -> Bs[n][k] bf16 ----
        #pragma unroll
        for (int v = 0; v < 2; ++v) {
            int r = sr + 16 * v;
            float4 f = *(const float4*)&Wb[(size_t)(k0 + r) * H + nc0 + scq * 4];
            Bs[scq * 4 + 0][r] = (unsigned short)f2bf_bits(f.x);
            Bs[scq * 4 + 1][r] = (unsigned short)f2bf_bits(f.y);
            Bs[scq * 4 + 2][r] = (unsigned short)f2bf_bits(f.z);
            Bs[scq * 4 + 3][r] = (unsigned short)f2bf_bits(f.w);
        }
        // ---- A-frags direct from fp32 X ----
        bf16x8 afr[2];
        #pragma unroll
        for (int mt = 0; mt < 2; ++mt) {
            const float* px = X + (size_t)(m0 + mt * 16 + ln) * H + k0 + quad * 8;
            float4 xa = *(const float4*)px;
            float4 xb = *(const float4*)(px + 4);
            uint4 pk = { pack_bf2(xa.x, xa.y), pack_bf2(xa.z, xa.w),
                         pack_bf2(xb.x, xb.y), pack_bf2(xb.z, xb.w) };
            afr[mt] = __builtin_bit_cast(bf16x8, pk);
        }
        __syncthreads();
        bf16x8 bfr[2];
        #pragma unroll
        for (int nt = 0; nt < 2; ++nt)
            bfr[nt] = *(const bf16x8*)&Bs[nw + nt * 16 + ln][quad * 8];
        #pragma unroll
        for (int mt = 0; mt < 2; ++mt)
            #pragma unroll
            for (int nt = 0; nt < 2; ++nt)
                acc[mt][nt] = __builtin_amdgcn_mfma_f32_16x16x32_bf16(
                    afr[mt], bfr[nt], acc[mt][nt], 0, 0, 0);
        __syncthreads();
    }

    // C/D: col = lane&15 (n), row = quad*4 + r (m)
    if (!isE) {
        float bv[2] = { b1[n0g + nw + ln], b1[n0g + nw + 16 + ln] };
        #pragma unroll
        for (int mt = 0; mt < 2; ++mt)
            #pragma unroll
            for (int nt = 0; nt < 2; ++nt) {
                int n = n0g + nw + nt * 16 + ln;
                #pragma unroll
                for (int r = 0; r < 4; ++r) {
                    int m = m0 + mt * 16 + quad * 4 + r;
                    Pxs[(size_t)m * H + n] = acc[mt][nt][r] + bv[nt];
                }
            }
    } else {
        #pragma unroll
        for (int mt = 0; mt < 2; ++mt)
            #pragma unroll
            for (int nt = 0; nt < 2; ++nt) {
                int n = nc0 + nw + nt * 16 + ln;
                #pragma unroll
                for (int r = 0; r < 4; ++r) {
                    int m = m0 + mt * 16 + quad * 4 + r;
                    Pxe[(size_t)m * H + n] = (unsigned short)f2bf_bits(acc[mt][nt][r]);
                }
            }
    }
}

// ---------------- Kernel 2: fused gelu + MFMA W2 reduction -------------------
// grid 2048: block = (b,i,jhalf). 4 waves x 2 m-tiles = 128 j per block.
__global__ __launch_bounds__(256, 6) void span_mfma_kernel(
    const float* __restrict__ Pxs, const unsigned short* __restrict__ Pxe,
    const unsigned short* __restrict__ Bfrag, const float* __restrict__ b2,
    float* __restrict__ out)
{
    __shared__ float xs[H];
    const int bi = blockIdx.x >> 1;          // b*L + i
    const int jh = blockIdx.x & 1;
    const int b = bi >> 8;
    const int tid = threadIdx.x;
    for (int t = tid; t < H; t += 256) xs[t] = Pxs[(size_t)bi * H + t];

    const int wave = tid >> 6;
    const int lane = tid & 63;
    const int n = lane & 15;
    const int quad = lane >> 4;
    const int j_base = jh * 128 + wave * 32;

    const unsigned short* xerow[2];
    #pragma unroll
    for (int t = 0; t < 2; ++t)
        xerow[t] = Pxe + (size_t)(b * L + j_base + t * 16 + n) * H;

    f32x4 acc[2] = {};
    __syncthreads();

    for (int kb = 0; kb < H / 32; ++kb) {
        const int k8 = kb * 32 + quad * 8;
        bf16x8 bfrag = *(const bf16x8*)(Bfrag + ((size_t)kb * 64 + lane) * 8);
        float4 xsa = *(const float4*)&xs[k8];
        float4 xsb = *(const float4*)&xs[k8 + 4];
        const float xsv[8] = {xsa.x, xsa.y, xsa.z, xsa.w, xsb.x, xsb.y, xsb.z, xsb.w};

        #pragma unroll
        for (int t = 0; t < 2; ++t) {
            uint4 xev = *(const uint4*)(xerow[t] + k8);
            const unsigned int xw[4] = {xev.x, xev.y, xev.z, xev.w};
            unsigned int pk[4];
            #pragma unroll
            for (int p = 0; p < 4; ++p) {
                float e0 = __builtin_bit_cast(float, xw[p] << 16);
                float e1 = __builtin_bit_cast(float, xw[p] & 0xffff0000u);
                float g0 = gelu_poly(xsv[2 * p + 0] + e0);
                float g1 = gelu_poly(xsv[2 * p + 1] + e1);
                pk[p] = pack_bf2(g0, g1);
            }
            uint4 pk4 = {pk[0], pk[1], pk[2], pk[3]};
            bf16x8 afrag = __builtin_bit_cast(bf16x8, pk4);
            acc[t] = __builtin_amdgcn_mfma_f32_16x16x32_bf16(afrag, bfrag, acc[t], 0, 0, 0);
        }
    }

    if (n < NL) {
        float b2v = b2[n];
        #pragma unroll
        for (int t = 0; t < 2; ++t)
            #pragma unroll
            for (int r = 0; r < 4; ++r) {
                int j = j_base + t * 16 + quad * 4 + r;
                out[((size_t)bi * L + j) * NL + n] = acc[t][r] + b2v;
            }
    }
}

// ---------------- Launch ------------------------------------------------------
extern "C" void kernel_launch(void* const* d_in, const int* in_sizes, int n_in,
                              void* d_out, int out_size, void* d_ws, size_t ws_size,
                              hipStream_t stream)
{
    (void)in_sizes; (void)n_in; (void)out_size; (void)ws_size;
    const float* X  = (const float*)d_in[0];
    const float* W1 = (const float*)d_in[1];
    const float* b1 = (const float*)d_in[2];
    const float* W2 = (const float*)d_in[3];
    const float* b2 = (const float*)d_in[4];
    float* out = (float*)d_out;

    char* ws = (char*)d_ws;
    float* Pxs = (float*)ws;                                              // 3 MB
    unsigned short* Pxe   = (unsigned short*)(ws + (size_t)NB * L * H * 4);  // 1.5 MB
    unsigned short* Bfrag = Pxe + (size_t)NB * L * H;                     // 24 KB

    gemm_fused<<<dim3(16, 25), 256, 0, stream>>>(X, W1, b1, W2, Pxs, Pxe, Bfrag);
    span_mfma_kernel<<<NB * L * 2, 256, 0, stream>>>(Pxs, Pxe, Bfrag, b2, out);
}

// Round 5
// 134.799 us; speedup vs baseline: 2.6124x; 1.1533x over previous
//
#include <hip/hip_runtime.h>
#include <math.h>

#define H 768
#define L 256
#define NB 4
#define NL 13

typedef _Float16 h2 __attribute__((ext_vector_type(2)));
typedef _Float16 half8 __attribute__((ext_vector_type(8)));
typedef float f32x4 __attribute__((ext_vector_type(4)));

// Packed-fp16 GELU: erf(x/sqrt2) ~= xc*P(v), v = (xc*xc)/8, xc = clamp(x,+-3.75).
// Coefficients rescaled so all are fp16-normal. ~11 v_pk ops per 2 elements.
__device__ inline h2 gelu_pk(h2 x) {
    const _Float16 kC = (_Float16)3.75f;
    h2 hi = {kC, kC}, lo = {(_Float16)-3.75f, (_Float16)-3.75f};
    h2 xc = __builtin_elementwise_min(__builtin_elementwise_max(x, lo), hi);
    h2 u = xc * xc;
    const _Float16 kE = (_Float16)0.125f;
    h2 ve = {kE, kE};
    h2 v = u * ve;
    const _Float16 d4v = (_Float16)0.0832840f,  d3v = (_Float16)-0.4335206f;
    const _Float16 d2v = (_Float16)0.8960128f,  d1v = (_Float16)-0.9876456f;
    const _Float16 d0v = (_Float16)0.7946463f;
    h2 d4 = {d4v, d4v}, d3 = {d3v, d3v}, d2 = {d2v, d2v}, d1 = {d1v, d1v}, d0 = {d0v, d0v};
    h2 p = v * (v * (v * (v * d4 + d3) + d2) + d1) + d0;   // contraction -> v_pk_fma_f16
    h2 t = xc * p;
    const _Float16 kH = (_Float16)0.5f;
    h2 halfv = {kH, kH};
    h2 hx = x * halfv;
    return hx * t + hx;
}

// ---------------- Prep: pack everything into MFMA fragment order -------------
// blk <  64          : Afrag[mt][kb][lane][8] = fp16 X[(mt*16+ln)*H + kb*32+q*8+u]
// 64 <= blk < 1216   : Bfrag1[ntg][kb][lane][8] = fp16 W1view[kb*32+q*8+u][ntg*16+ln]
//                      (W1view[k][n'] = W1[k + H*(n'>=H)][n'%H], n' in [0,1536))
// blk >= 1216 (16)   : Bfrag2[kb][lane][8] = fp16 W2[k][n] (n=ln<13 else 0)
__global__ __launch_bounds__(256) void prep_kernel(
    const float* __restrict__ X, const float* __restrict__ W1,
    const float* __restrict__ W2,
    _Float16* __restrict__ Afrag, _Float16* __restrict__ Bfrag1,
    _Float16* __restrict__ Bfrag2)
{
    __shared__ __align__(16) unsigned char smem[16 * 784 * 2];
    const int blk = blockIdx.x;
    const int tid = threadIdx.x;

    if (blk < 64) {
        // ---- X rows [mt*16, mt*16+16) -> LDS fp16 (pitch 784) -> Afrag ----
        _Float16* T = (_Float16*)smem;
        const int mt = blk;
        const int row = tid >> 4, colg = tid & 15;
        #pragma unroll
        for (int cc = 0; cc < 12; ++cc) {
            int c4 = (colg + cc * 16) * 4;
            float4 f = *(const float4*)&X[(size_t)(mt * 16 + row) * H + c4];
            _Float16* d = T + row * 784 + c4;
            d[0] = (_Float16)f.x; d[1] = (_Float16)f.y;
            d[2] = (_Float16)f.z; d[3] = (_Float16)f.w;
        }
        __syncthreads();
        // frag write: 12 rounds x 2 kb; thread -> (kb, lane, u4)
        #pragma unroll
        for (int rr = 0; rr < 12; ++rr) {
            int kb = rr * 2 + (tid >> 7);
            int sub = tid & 127;
            int lane = sub >> 1, u4 = (sub & 1) * 4;
            int ln = lane & 15, q = lane >> 4;
            const _Float16* s = T + ln * 784 + kb * 32 + q * 8 + u4;
            ushort4 o = { *(const unsigned short*)&s[0], *(const unsigned short*)&s[1],
                          *(const unsigned short*)&s[2], *(const unsigned short*)&s[3] };
            *(ushort4*)&Afrag[(((size_t)mt * 24 + kb) * 64 + lane) * 8 + u4] = o;
        }
    } else if (blk < 64 + 1152) {
        // ---- W1 32x32 tile -> LDS fp16 transpose -> Bfrag1 ----
        _Float16* T = (_Float16*)smem;       // tile[32][36], [k][n]
        const int t2 = blk - 64;
        const int kb = t2 % 24, ng = t2 / 24;          // ng: n'-group of 32
        const int n0p = ng * 32;
        const float* Wb = W1 + ((n0p >= H) ? (size_t)H * H : 0);
        const int c0 = n0p - ((n0p >= H) ? H : 0);
        const int row = tid >> 3, c4 = (tid & 7) * 4;  // 32 rows x 32 cols
        float4 f = *(const float4*)&Wb[(size_t)(kb * 32 + row) * H + c0 + c4];
        _Float16* d = T + row * 36 + c4;
        d[0] = (_Float16)f.x; d[1] = (_Float16)f.y;
        d[2] = (_Float16)f.z; d[3] = (_Float16)f.w;
        __syncthreads();
        // thread -> (nts, lane, u4): read 4 k-rows (scattered LDS), coalesced global write
        int u4 = (tid & 1) * 4;
        int lane = (tid >> 1) & 63;
        int nts = tid >> 7;
        int ln = lane & 15, q = lane >> 4;
        ushort4 o;
        unsigned short* os = (unsigned short*)&o;
        #pragma unroll
        for (int i = 0; i < 4; ++i)
            os[i] = *(const unsigned short*)&T[(q * 8 + u4 + i) * 36 + nts * 16 + ln];
        int ntg = (n0p >> 4) + nts;
        *(ushort4*)&Bfrag1[(((size_t)ntg * 24 + kb) * 64 + lane) * 8 + u4] = o;
    } else {
        // ---- W2 -> Bfrag2 fp16 ----
        int base = (blk - 64 - 1152) * 768 + tid;
        #pragma unroll
        for (int r = 0; r < 3; ++r) {
            int idx = base + r * 256;            // < 12288
            int u = idx & 7;
            int lane = (idx >> 3) & 63;
            int kb = idx >> 9;
            int k = kb * 32 + ((lane >> 4) << 3) + u;
            int n = lane & 15;
            float v = (n < NL) ? W2[(size_t)k * NL + n] : 0.f;
            Bfrag2[idx] = (_Float16)v;
        }
    }
}

// ---------------- Stage 1: MFMA GEMM, fragment-direct, no LDS ----------------
// grid (16, 24). C[m][n'] over K=768; n'<768 -> Pxs2 fp16 (+b1), else Pxe fp16.
__global__ __launch_bounds__(256) void gemm_mfma(
    const _Float16* __restrict__ Afrag, const _Float16* __restrict__ Bfrag1,
    const float* __restrict__ b1, _Float16* __restrict__ Pxs2,
    _Float16* __restrict__ Pxe)
{
    const int tid = threadIdx.x;
    const int w = tid >> 6, lane = tid & 63;
    const int ln = lane & 15, quad = lane >> 4;
    const int m0 = blockIdx.x * 64 + (w & 1) * 32;
    const int n0g = blockIdx.y * 64 + (w >> 1) * 32;   // n' in [0,1536)
    const int mt0 = m0 >> 4, ntg0 = n0g >> 4;

    const half8* pa0 = (const half8*)(Afrag + (((size_t)mt0 * 24) * 64 + lane) * 8);
    const half8* pa1 = (const half8*)(Afrag + ((((size_t)mt0 + 1) * 24) * 64 + lane) * 8);
    const half8* pb0 = (const half8*)(Bfrag1 + (((size_t)ntg0 * 24) * 64 + lane) * 8);
    const half8* pb1 = (const half8*)(Bfrag1 + ((((size_t)ntg0 + 1) * 24) * 64 + lane) * 8);

    f32x4 acc[2][2] = {};
    #pragma unroll 4
    for (int kb = 0; kb < 24; ++kb) {
        half8 a0 = pa0[kb * 64];
        half8 a1 = pa1[kb * 64];
        half8 b0 = pb0[kb * 64];
        half8 b1v = pb1[kb * 64];
        acc[0][0] = __builtin_amdgcn_mfma_f32_16x16x32_f16(a0, b0, acc[0][0], 0, 0, 0);
        acc[0][1] = __builtin_amdgcn_mfma_f32_16x16x32_f16(a0, b1v, acc[0][1], 0, 0, 0);
        acc[1][0] = __builtin_amdgcn_mfma_f32_16x16x32_f16(a1, b0, acc[1][0], 0, 0, 0);
        acc[1][1] = __builtin_amdgcn_mfma_f32_16x16x32_f16(a1, b1v, acc[1][1], 0, 0, 0);
    }

    // C/D: col = lane&15 (n), row = quad*4 + r (m). Block's n-range is uniform-side.
    if (n0g < H) {
        float bv[2] = { b1[n0g + ln], b1[n0g + 16 + ln] };
        #pragma unroll
        for (int mt = 0; mt < 2; ++mt)
            #pragma unroll
            for (int nt = 0; nt < 2; ++nt) {
                int n = n0g + nt * 16 + ln;
                #pragma unroll
                for (int r = 0; r < 4; ++r) {
                    int m = m0 + mt * 16 + quad * 4 + r;
                    Pxs2[(size_t)m * H + n] = (_Float16)(acc[mt][nt][r] + bv[nt]);
                }
            }
    } else {
        #pragma unroll
        for (int mt = 0; mt < 2; ++mt)
            #pragma unroll
            for (int nt = 0; nt < 2; ++nt) {
                int n = n0g - H + nt * 16 + ln;
                #pragma unroll
                for (int r = 0; r < 4; ++r) {
                    int m = m0 + mt * 16 + quad * 4 + r;
                    Pxe[(size_t)m * H + n] = (_Float16)acc[mt][nt][r];
                }
            }
    }
}

// ---------------- Stage 2: packed-fp16 gelu + MFMA W2 reduction --------------
// grid 2048: block = (b,i,jhalf). 4 waves x 2 m-tiles = 128 j per block.
__global__ __launch_bounds__(256, 6) void span_mfma_kernel(
    const _Float16* __restrict__ Pxs2, const _Float16* __restrict__ Pxe,
    const _Float16* __restrict__ Bfrag2, const float* __restrict__ b2,
    float* __restrict__ out)
{
    __shared__ unsigned int xs2[H / 2];     // fp16 pairs
    const int bi = blockIdx.x >> 1;          // b*L + i
    const int jh = blockIdx.x & 1;
    const int b = bi >> 8;
    const int tid = threadIdx.x;
    const unsigned int* xrow = (const unsigned int*)(Pxs2 + (size_t)bi * H);
    for (int t = tid; t < H / 2; t += 256) xs2[t] = xrow[t];

    const int wave = tid >> 6;
    const int lane = tid & 63;
    const int n = lane & 15;
    const int quad = lane >> 4;
    const int j_base = jh * 128 + wave * 32;

    const _Float16* xerow[2];
    #pragma unroll
    for (int t = 0; t < 2; ++t)
        xerow[t] = Pxe + (size_t)(b * L + j_base + t * 16 + n) * H;

    f32x4 acc[2] = {};
    __syncthreads();

    for (int kb = 0; kb < H / 32; ++kb) {
        const int k8 = kb * 32 + quad * 8;
        half8 bfrag = *(const half8*)(Bfrag2 + ((size_t)kb * 64 + lane) * 8);
        uint4 xsd = *(const uint4*)&xs2[k8 >> 1];
        h2 xsp[4] = { __builtin_bit_cast(h2, xsd.x), __builtin_bit_cast(h2, xsd.y),
                      __builtin_bit_cast(h2, xsd.z), __builtin_bit_cast(h2, xsd.w) };

        #pragma unroll
        for (int t = 0; t < 2; ++t) {
            uint4 xev = *(const uint4*)(xerow[t] + k8);
            h2 xep[4] = { __builtin_bit_cast(h2, xev.x), __builtin_bit_cast(h2, xev.y),
                          __builtin_bit_cast(h2, xev.z), __builtin_bit_cast(h2, xev.w) };
            unsigned int pk[4];
            #pragma unroll
            for (int p = 0; p < 4; ++p) {
                h2 g = gelu_pk(xsp[p] + xep[p]);
                pk[p] = __builtin_bit_cast(unsigned int, g);
            }
            uint4 pk4 = {pk[0], pk[1], pk[2], pk[3]};
            half8 afrag = __builtin_bit_cast(half8, pk4);
            acc[t] = __builtin_amdgcn_mfma_f32_16x16x32_f16(afrag, bfrag, acc[t], 0, 0, 0);
        }
    }

    if (n < NL) {
        float b2v = b2[n];
        #pragma unroll
        for (int t = 0; t < 2; ++t)
            #pragma unroll
            for (int r = 0; r < 4; ++r) {
                int j = j_base + t * 16 + quad * 4 + r;
                out[((size_t)bi * L + j) * NL + n] = acc[t][r] + b2v;
            }
    }
}

// ---------------- Launch ------------------------------------------------------
extern "C" void kernel_launch(void* const* d_in, const int* in_sizes, int n_in,
                              void* d_out, int out_size, void* d_ws, size_t ws_size,
                              hipStream_t stream)
{
    (void)in_sizes; (void)n_in; (void)out_size; (void)ws_size;
    const float* X  = (const float*)d_in[0];
    const float* W1 = (const float*)d_in[1];
    const float* b1 = (const float*)d_in[2];
    const float* W2 = (const float*)d_in[3];
    const float* b2 = (const float*)d_in[4];
    float* out = (float*)d_out;

    char* ws = (char*)d_ws;
    _Float16* Pxs2   = (_Float16*)ws;                          // 1.5 MB
    _Float16* Pxe    = Pxs2 + (size_t)NB * L * H;              // 1.5 MB
    _Float16* Afrag  = Pxe + (size_t)NB * L * H;               // 1.5 MB
    _Float16* Bfrag1 = Afrag + (size_t)NB * L * H;             // 2.25 MB
    _Float16* Bfrag2 = Bfrag1 + (size_t)2 * H * H;             // 24 KB

    prep_kernel<<<64 + 1152 + 16, 256, 0, stream>>>(X, W1, W2, Afrag, Bfrag1, Bfrag2);
    gemm_mfma<<<dim3(16, 24), 256, 0, stream>>>(Afrag, Bfrag1, b1, Pxs2, Pxe);
    span_mfma_kernel<<<NB * L * 2, 256, 0, stream>>>(Pxs2, Pxe, Bfrag2, b2, out);
}